// Round 2
// baseline (1305.273 us; speedup 1.0000x reference)
//
#include <hip/hip_runtime.h>
#include <math.h>

// ---------------- problem constants ----------------
constexpr int Bn  = 128;      // batch
constexpr int Kd  = 65536;    // magnitude dim (phase half of feats is zeros)
constexpr int F1  = 128;
constexpr int F2  = 64;
constexpr int NM  = 3;        // number of ops matrices
constexpr int Qd  = 256;
constexpr int NCH = 256;      // split-K chunks for big GEMM
constexpr int KC  = 256;      // k per chunk
constexpr int MSZ = 256 * 256;
constexpr int NSB = 32;       // barrier slots per matrix

// quintic (Muon) Newton-Schulz coefficients
#define QA 3.4445f
#define QB (-4.7750f)
#define QC 2.0315f

// ---------------- ws layout (float offsets) ----------------
constexpr size_t OFF_H1P  = 0;                                   // 4,194,304
constexpr size_t OFF_H1   = OFF_H1P + (size_t)NCH * Bn * F1;     // 16384
constexpr size_t OFF_SEL  = OFF_H1 + (size_t)Bn * F1;            // 128 (int)
constexpr size_t OFF_PART = OFF_SEL + 128;                       // 192
constexpr size_t OFF_BAR  = OFF_PART + 192;                      // 96 u32 -> pad 128
constexpr size_t OFF_XA   = OFF_BAR + 128;                       // 3*MSZ (16B aligned)
constexpr size_t OFF_XB   = OFF_XA + (size_t)NM * MSZ;
constexpr size_t OFF_AM   = OFF_XB + (size_t)NM * MSZ;

// ---------------- K1: split-K magnitude GEMM (unchanged) ----------------
__global__ __launch_bounds__(256) void k_gemm1(const float* __restrict__ sp,
                                               const float* __restrict__ W1,
                                               float* __restrict__ h1p) {
  __shared__ float As[128][33];
  __shared__ float Ws[128][33];
  const int t  = threadIdx.x;
  const int ch = blockIdx.x;
  const int k0 = ch * KC;
  const int r0 = (t >> 4) * 8;
  const int cw = t & 15;
  float acc[8][8];
#pragma unroll
  for (int r = 0; r < 8; ++r)
#pragma unroll
    for (int c = 0; c < 8; ++c) acc[r][c] = 0.f;

  const int kk = t & 31, bq = t >> 5;
  for (int kt = 0; kt < 8; ++kt) {
    __syncthreads();
    const int kb = k0 + kt * 32 + kk;
#pragma unroll
    for (int bb = bq; bb < 128; bb += 8) {
      As[bb][kk] = fabsf(sp[bb * Kd + kb]);
      Ws[bb][kk] = W1[bb * (2 * Kd) + kb];
    }
    __syncthreads();
#pragma unroll
    for (int q = 0; q < 32; ++q) {
      float a[8], w[8];
#pragma unroll
      for (int r = 0; r < 8; ++r) a[r] = As[r0 + r][q];
#pragma unroll
      for (int c = 0; c < 8; ++c) w[c] = Ws[cw + 16 * c][q];
#pragma unroll
      for (int r = 0; r < 8; ++r)
#pragma unroll
        for (int c = 0; c < 8; ++c) acc[r][c] += a[r] * w[c];
    }
  }
  float* outp = h1p + (size_t)ch * (Bn * F1);
#pragma unroll
  for (int r = 0; r < 8; ++r)
#pragma unroll
    for (int c = 0; c < 8; ++c)
      outp[(r0 + r) * F1 + cw + 16 * c] = acc[r][c];
}

// ---------------- K1b: reduce partials + bias + relu (256 blocks now) ----------------
__global__ __launch_bounds__(256) void k_red(const float* __restrict__ h1p,
                                             const float* __restrict__ b1,
                                             float* __restrict__ h1) {
  const int t = threadIdx.x;
  const int ol = t & 63;
  const int g = t >> 6;                      // 4 chunk-groups
  const int o = blockIdx.x * 64 + ol;        // 256 blocks x 64 outputs
  double s = 0.0;
#pragma unroll 8
  for (int c = g * 64; c < g * 64 + 64; ++c)
    s += (double)h1p[(size_t)c * (Bn * F1) + o];
  __shared__ double red[4][64];
  red[g][ol] = s;
  __syncthreads();
  if (g == 0) {
    const double v = red[0][ol] + red[1][ol] + red[2][ol] + red[3][ol];
    const float r = (float)v + b1[o & 127];
    h1[o] = fmaxf(r, 0.f);
  }
}

// ---------------- K2: small MLP + syndrome + selection (unchanged) ----------------
__global__ __launch_bounds__(256) void k_mlp(const float* __restrict__ h1,
                                             const float* __restrict__ W2,
                                             const float* __restrict__ b2,
                                             const float* __restrict__ W3,
                                             const float* __restrict__ b3,
                                             int* __restrict__ sel) {
  const int t = threadIdx.x;
  const int b0 = blockIdx.x * 16;
  __shared__ float h2s[16 * 64];
  for (int o = t; o < 16 * 64; o += 256) {
    const int bl = o >> 6, j = o & 63;
    const float* hr = h1 + (b0 + bl) * F1;
    const float* wr = W2 + j * F1;
    float s = b2[j];
    for (int k = 0; k < F1; ++k) s += hr[k] * wr[k];
    h2s[o] = fmaxf(s, 0.f);
  }
  __syncthreads();
  if (t < 16) {
    const int b = b0 + t;
    float best = -1.f;
    int bi = 0;
    bool needed = false;
    for (int j = 0; j < 8; ++j) {
      double s = (double)b3[j];
      const float* wr = W3 + j * F2;
      for (int k = 0; k < F2; ++k) s += (double)h2s[t * F2 + k] * (double)wr[k];
      const float a = fabsf((float)s);
      if (a > 1e-4f) needed = true;
      if (a > best) { best = a; bi = j; }
    }
    sel[b] = needed ? (bi % NM) : -1;
  }
}

// ---------------- software grid barrier (per-matrix, 64 blocks) ----------------
__device__ __forceinline__ void gbar(unsigned int* cnt) {
  __syncthreads();
  __threadfence();                 // release this block's writes device-wide
  if (threadIdx.x == 0) {
    atomicAdd(cnt, 1u);            // device-scope by default on gfx950
    while (atomicAdd(cnt, 0u) < 64u) __builtin_amdgcn_s_sleep(2);
  }
  __syncthreads();
  __threadfence();                 // acquire: invalidate stale L1/L2 before reads
}

// ---------------- K3: fused Newton-Schulz polar factor ----------------
// grid = 192 blocks (3 matrices x 64 row-groups), all co-resident (<=256 CUs).
// Per matrix: norm -> scale -> 8 quintic iters (2 barriers each) -> 4 cubic.
__global__ __launch_bounds__(256, 1) void k_ns(const float* __restrict__ ops,
                                               float* __restrict__ Xa,
                                               float* __restrict__ Xb,
                                               float* __restrict__ Am,
                                               float* __restrict__ part,
                                               unsigned int* __restrict__ bars) {
  const int t = threadIdx.x;
  const int m = blockIdx.x >> 6;
  const int g = blockIdx.x & 63;
  const int i0 = g * 4;
  const float* C = ops + (size_t)m * MSZ;
  float* X  = Xa + (size_t)m * MSZ;
  float* Xn = Xb + (size_t)m * MSZ;
  float* A  = Am + (size_t)m * MSZ;
  unsigned int* bar = bars + m * NSB;
  int ph = 0;

  __shared__ float pt[256][4];
  __shared__ float ys[4][256];
  __shared__ float red[256];
  __shared__ float sbc;

  // ---- N0: partial sum of squares over this block's 1024-element slice ----
  {
    const float4 v = ((const float4*)(C + g * 1024))[t];
    red[t] = v.x * v.x + v.y * v.y + v.z * v.z + v.w * v.w;
    __syncthreads();
    for (int o = 128; o > 0; o >>= 1) {
      if (t < o) red[t] += red[t + o];
      __syncthreads();
    }
    if (t == 0) part[m * 64 + g] = red[0];
  }
  gbar(&bar[ph++]);

  // ---- N1: redundant deterministic scale + scale X into Xa ----
  {
    float v = (t < 64) ? part[m * 64 + t] : 0.f;
#pragma unroll
    for (int o = 32; o > 0; o >>= 1) v += __shfl_down(v, o, 64);
    if (t == 0) sbc = 1.f / (0.15f * sqrtf(v));  // 1/(1.2 * 2||F||/sqrt(256))
    __syncthreads();
    const float sc = sbc;
    float4 v4 = ((const float4*)(C + g * 1024))[t];
    v4.x *= sc; v4.y *= sc; v4.z *= sc; v4.w *= sc;
    ((float4*)(X + g * 1024))[t] = v4;
  }
  gbar(&bar[ph++]);

  // ---- 8 quintic + 4 cubic iterations, 2 barriers each ----
  for (int it = 0; it < 12; ++it) {
    const bool quint = (it < 8);

    // phase A: A = X^T X (this block computes rows i0..i0+3 of A)
    {
      const float4 cv = *(const float4*)(X + t * 256 + i0);  // X[t][i0..i0+3]
      pt[t][0] = cv.x; pt[t][1] = cv.y; pt[t][2] = cv.z; pt[t][3] = cv.w;
      __syncthreads();
      float a0 = 0, a1 = 0, a2 = 0, a3 = 0;
#pragma unroll 4
      for (int k = 0; k < 256; ++k) {
        const float v = X[k * 256 + t];
        const float4 c = *(const float4*)&pt[k][0];
        a0 += c.x * v; a1 += c.y * v; a2 += c.z * v; a3 += c.w * v;
      }
      A[(i0 + 0) * 256 + t] = a0;
      A[(i0 + 1) * 256 + t] = a1;
      A[(i0 + 2) * 256 + t] = a2;
      A[(i0 + 3) * 256 + t] = a3;
    }
    gbar(&bar[ph++]);

    // phase B: Y = X*A rows, then X' = QA*X + QB*Y + QC*(Y*A)  (or cubic)
    {
#pragma unroll
      for (int r = 0; r < 4; ++r) pt[t][r] = X[(i0 + r) * 256 + t];  // X rows
      __syncthreads();
      float y0 = 0, y1 = 0, y2 = 0, y3 = 0;
#pragma unroll 4
      for (int k = 0; k < 256; ++k) {
        const float v = A[k * 256 + t];
        const float4 c = *(const float4*)&pt[k][0];
        y0 += c.x * v; y1 += c.y * v; y2 += c.z * v; y3 += c.w * v;
      }
      if (quint) {
        ys[0][t] = y0; ys[1][t] = y1; ys[2][t] = y2; ys[3][t] = y3;
        __syncthreads();
        float z0 = 0, z1 = 0, z2 = 0, z3 = 0;
#pragma unroll 4
        for (int k = 0; k < 256; ++k) {
          const float v = A[k * 256 + t];
          z0 += ys[0][k] * v; z1 += ys[1][k] * v;
          z2 += ys[2][k] * v; z3 += ys[3][k] * v;
        }
        Xn[(i0 + 0) * 256 + t] = QA * pt[t][0] + QB * y0 + QC * z0;
        Xn[(i0 + 1) * 256 + t] = QA * pt[t][1] + QB * y1 + QC * z1;
        Xn[(i0 + 2) * 256 + t] = QA * pt[t][2] + QB * y2 + QC * z2;
        Xn[(i0 + 3) * 256 + t] = QA * pt[t][3] + QB * y3 + QC * z3;
      } else {
        Xn[(i0 + 0) * 256 + t] = 1.5f * pt[t][0] - 0.5f * y0;
        Xn[(i0 + 1) * 256 + t] = 1.5f * pt[t][1] - 0.5f * y1;
        Xn[(i0 + 2) * 256 + t] = 1.5f * pt[t][2] - 0.5f * y2;
        Xn[(i0 + 3) * 256 + t] = 1.5f * pt[t][3] - 0.5f * y3;
      }
    }
    gbar(&bar[ph++]);
    float* tmp = X; X = Xn; Xn = tmp;
  }
  // 12 swaps -> final polar factor in Xa
}

// ---------------- K4: output assembly (unchanged) ----------------
__global__ __launch_bounds__(256) void k_out(const float* __restrict__ sp,
                                             const float* __restrict__ P,
                                             const int* __restrict__ sel,
                                             float* __restrict__ out) {
  const int t = threadIdx.x;
  if (blockIdx.x < 128) {
    const int b = blockIdx.x;
    __shared__ float hd[256];
    hd[t] = sp[(size_t)b * Kd + t];
    __syncthreads();
    const int s = sel[b];
    if (s < 0) {
      out[(size_t)b * Kd + t] = hd[t];
    } else {
      const float4* prow = (const float4*)(P + (size_t)s * MSZ + t * 256);
      float acc = 0.f;
#pragma unroll 8
      for (int j4 = 0; j4 < 64; ++j4) {
        const float4 p = prow[j4];
        acc += p.x * hd[4 * j4 + 0] + p.y * hd[4 * j4 + 1] +
               p.z * hd[4 * j4 + 2] + p.w * hd[4 * j4 + 3];
      }
      out[(size_t)b * Kd + t] = hd[t] + 0.1f * acc;
    }
  } else {
    const int ci = blockIdx.x - 128;
    const float4* in4 = (const float4*)sp;
    float4* out4 = (float4*)out;
    const int total = Bn * (Kd / 4);
    for (int i = ci * 256 + t; i < total; i += 2048 * 256) {
      const int pos = i & ((Kd / 4) - 1);
      if (pos >= Qd / 4) out4[i] = in4[i];
    }
  }
}

// ---------------- host ----------------
extern "C" void kernel_launch(void* const* d_in, const int* in_sizes, int n_in,
                              void* d_out, int out_size, void* d_ws, size_t ws_size,
                              hipStream_t stream) {
  (void)in_sizes; (void)n_in; (void)out_size; (void)ws_size;
  const float* sp = (const float*)d_in[0];
  const float* W1 = (const float*)d_in[1];
  const float* b1 = (const float*)d_in[2];
  const float* W2 = (const float*)d_in[3];
  const float* b2 = (const float*)d_in[4];
  const float* W3 = (const float*)d_in[5];
  const float* b3 = (const float*)d_in[6];
  const float* ops = (const float*)d_in[7];
  float* out = (float*)d_out;
  float* ws = (float*)d_ws;

  float* h1p = ws + OFF_H1P;
  float* h1  = ws + OFF_H1;
  int*   sel = (int*)(ws + OFF_SEL);
  float* part = ws + OFF_PART;
  unsigned int* bars = (unsigned int*)(ws + OFF_BAR);
  float* Xa  = ws + OFF_XA;
  float* Xb  = ws + OFF_XB;
  float* Am  = ws + OFF_AM;

  hipMemsetAsync(bars, 0, NM * NSB * sizeof(unsigned int), stream);

  k_gemm1<<<NCH, 256, 0, stream>>>(sp, W1, h1p);
  k_red<<<256, 256, 0, stream>>>(h1p, b1, h1);
  k_mlp<<<8, 256, 0, stream>>>(h1, W2, b2, W3, b3, sel);
  k_ns<<<192, 256, 0, stream>>>(ops, Xa, Xb, Am, part, bars);
  k_out<<<128 + 2048, 256, 0, stream>>>(sp, Xa, sel, out);
}

// Round 3
// 334.108 us; speedup vs baseline: 3.9067x; 3.9067x over previous
//
#include <hip/hip_runtime.h>
#include <math.h>

// ---------------- problem constants ----------------
constexpr int Bn  = 128;      // batch
constexpr int Kd  = 65536;    // magnitude dim (phase half of feats is zeros)
constexpr int F1  = 128;
constexpr int F2  = 64;
constexpr int NM  = 3;        // number of ops matrices
constexpr int Qd  = 256;
constexpr int NCH = 256;      // split-K chunks for big GEMM
constexpr int KC  = 256;      // k per chunk
constexpr int MSZ = 256 * 256;

// quintic (Muon) Newton-Schulz coefficients
#define QA 3.4445f
#define QB (-4.7750f)
#define QC 2.0315f

// ---------------- ws layout (float offsets) ----------------
constexpr size_t OFF_H1P  = 0;                                   // 4,194,304
constexpr size_t OFF_H1   = OFF_H1P + (size_t)NCH * Bn * F1;     // 16384
constexpr size_t OFF_SEL  = OFF_H1 + (size_t)Bn * F1;            // 128 (int)
constexpr size_t OFF_PART = OFF_SEL + 128;                       // 192 -> pad 256
constexpr size_t OFF_XA   = OFF_PART + 256;
constexpr size_t OFF_XB   = OFF_XA + (size_t)NM * MSZ;
constexpr size_t OFF_AM   = OFF_XB + (size_t)NM * MSZ;

// ---------------- K1: split-K magnitude GEMM ----------------
__global__ __launch_bounds__(256) void k_gemm1(const float* __restrict__ sp,
                                               const float* __restrict__ W1,
                                               float* __restrict__ h1p) {
  __shared__ float As[128][33];
  __shared__ float Ws[128][33];
  const int t  = threadIdx.x;
  const int ch = blockIdx.x;
  const int k0 = ch * KC;
  const int r0 = (t >> 4) * 8;
  const int cw = t & 15;
  float acc[8][8];
#pragma unroll
  for (int r = 0; r < 8; ++r)
#pragma unroll
    for (int c = 0; c < 8; ++c) acc[r][c] = 0.f;

  const int kk = t & 31, bq = t >> 5;
  for (int kt = 0; kt < 8; ++kt) {
    __syncthreads();
    const int kb = k0 + kt * 32 + kk;
#pragma unroll
    for (int bb = bq; bb < 128; bb += 8) {
      As[bb][kk] = fabsf(sp[bb * Kd + kb]);
      Ws[bb][kk] = W1[bb * (2 * Kd) + kb];
    }
    __syncthreads();
#pragma unroll
    for (int q = 0; q < 32; ++q) {
      float a[8], w[8];
#pragma unroll
      for (int r = 0; r < 8; ++r) a[r] = As[r0 + r][q];
#pragma unroll
      for (int c = 0; c < 8; ++c) w[c] = Ws[cw + 16 * c][q];
#pragma unroll
      for (int r = 0; r < 8; ++r)
#pragma unroll
        for (int c = 0; c < 8; ++c) acc[r][c] += a[r] * w[c];
    }
  }
  float* outp = h1p + (size_t)ch * (Bn * F1);
#pragma unroll
  for (int r = 0; r < 8; ++r)
#pragma unroll
    for (int c = 0; c < 8; ++c)
      outp[(r0 + r) * F1 + cw + 16 * c] = acc[r][c];
}

// ---------------- K1b: reduce partials + bias + relu ----------------
__global__ __launch_bounds__(256) void k_red(const float* __restrict__ h1p,
                                             const float* __restrict__ b1,
                                             float* __restrict__ h1) {
  const int t = threadIdx.x;
  const int ol = t & 63;
  const int g = t >> 6;
  const int o = blockIdx.x * 64 + ol;
  double s = 0.0;
#pragma unroll 8
  for (int c = g * 64; c < g * 64 + 64; ++c)
    s += (double)h1p[(size_t)c * (Bn * F1) + o];
  __shared__ double red[4][64];
  red[g][ol] = s;
  __syncthreads();
  if (g == 0) {
    const double v = red[0][ol] + red[1][ol] + red[2][ol] + red[3][ol];
    const float r = (float)v + b1[o & 127];
    h1[o] = fmaxf(r, 0.f);
  }
}

// ---------------- K2: small MLP + syndrome + selection ----------------
__global__ __launch_bounds__(256) void k_mlp(const float* __restrict__ h1,
                                             const float* __restrict__ W2,
                                             const float* __restrict__ b2,
                                             const float* __restrict__ W3,
                                             const float* __restrict__ b3,
                                             int* __restrict__ sel) {
  const int t = threadIdx.x;
  const int b0 = blockIdx.x * 16;
  __shared__ float h2s[16 * 64];
  for (int o = t; o < 16 * 64; o += 256) {
    const int bl = o >> 6, j = o & 63;
    const float* hr = h1 + (b0 + bl) * F1;
    const float* wr = W2 + j * F1;
    float s = b2[j];
    for (int k = 0; k < F1; ++k) s += hr[k] * wr[k];
    h2s[o] = fmaxf(s, 0.f);
  }
  __syncthreads();
  if (t < 16) {
    const int b = b0 + t;
    float best = -1.f;
    int bi = 0;
    bool needed = false;
    for (int j = 0; j < 8; ++j) {
      double s = (double)b3[j];
      const float* wr = W3 + j * F2;
      for (int k = 0; k < F2; ++k) s += (double)h2s[t * F2 + k] * (double)wr[k];
      const float a = fabsf((float)s);
      if (a > 1e-4f) needed = true;
      if (a > best) { best = a; bi = j; }
    }
    sel[b] = needed ? (bi % NM) : -1;
  }
}

// ---------------- NS setup: partial sum of squares (192 blocks) ----------------
__global__ __launch_bounds__(256) void k_sumsq(const float* __restrict__ ops,
                                               float* __restrict__ part) {
  const int m = blockIdx.x >> 6, g = blockIdx.x & 63;
  const int t = threadIdx.x;
  const float4 v = ((const float4*)(ops + (size_t)m * MSZ + g * 1024))[t];
  __shared__ float red[256];
  red[t] = v.x * v.x + v.y * v.y + v.z * v.z + v.w * v.w;
  __syncthreads();
  for (int o = 128; o > 0; o >>= 1) {
    if (t < o) red[t] += red[t + o];
    __syncthreads();
  }
  if (t == 0) part[m * 64 + g] = red[0];
}

// ---------------- NS setup: redundant scale reduce + scale (192 blocks) ----------------
__global__ __launch_bounds__(256) void k_scale(const float* __restrict__ ops,
                                               const float* __restrict__ part,
                                               float* __restrict__ X) {
  const int m = blockIdx.x >> 6, g = blockIdx.x & 63;
  const int t = threadIdx.x;
  __shared__ float sbc;
  float v = (t < 64) ? part[m * 64 + t] : 0.f;
  if (t < 64) {
#pragma unroll
    for (int o = 32; o > 0; o >>= 1) v += __shfl_down(v, o, 64);
  }
  if (t == 0) sbc = 1.f / (0.15f * sqrtf(v));  // 1/(1.2 * 2||F||/sqrt(256))
  __syncthreads();
  const float sc = sbc;
  float4 v4 = ((const float4*)(ops + (size_t)m * MSZ + g * 1024))[t];
  v4.x *= sc; v4.y *= sc; v4.z *= sc; v4.w *= sc;
  ((float4*)(X + (size_t)m * MSZ + g * 1024))[t] = v4;
}

// ---------------- NS phase A: A = X^T X (192 blocks, 4 rows each) ----------------
// Thread (tq=t>>6, tc=t&63): 4x4 tile rows i0..i0+3, cols 4tc..4tc+3, k in [64tq,64tq+64)
__global__ __launch_bounds__(256) void k_pA(const float* __restrict__ X,
                                            float* __restrict__ A) {
  const int m = blockIdx.x >> 6, g = blockIdx.x & 63, i0 = g * 4;
  const int t = threadIdx.x, tq = t >> 6, tc = t & 63;
  const float* Xm = X + (size_t)m * MSZ;
  float* Am = A + (size_t)m * MSZ;
  __shared__ float pt[4][260];        // pt[q][kk*4+i] = X[q*64+kk][i0+i]
  __shared__ float red[4][64][17];

  {  // stage the 4-column slice, k = t
    const float4 cv = *(const float4*)(Xm + t * 256 + i0);
    float* d = &pt[t >> 6][(t & 63) * 4];
    d[0] = cv.x; d[1] = cv.y; d[2] = cv.z; d[3] = cv.w;
  }
  __syncthreads();

  const float4* X4 = (const float4*)Xm;
  float a00=0,a01=0,a02=0,a03=0, a10=0,a11=0,a12=0,a13=0;
  float a20=0,a21=0,a22=0,a23=0, a30=0,a31=0,a32=0,a33=0;
  const int kbase = tq * 64;
#pragma unroll 8
  for (int kk = 0; kk < 64; ++kk) {
    const float4 xv = X4[(kbase + kk) * 64 + tc];
    const float4 pv = *(const float4*)&pt[tq][kk * 4];
    a00 += pv.x*xv.x; a01 += pv.x*xv.y; a02 += pv.x*xv.z; a03 += pv.x*xv.w;
    a10 += pv.y*xv.x; a11 += pv.y*xv.y; a12 += pv.y*xv.z; a13 += pv.y*xv.w;
    a20 += pv.z*xv.x; a21 += pv.z*xv.y; a22 += pv.z*xv.z; a23 += pv.z*xv.w;
    a30 += pv.w*xv.x; a31 += pv.w*xv.y; a32 += pv.w*xv.z; a33 += pv.w*xv.w;
  }
  float* rr = &red[tq][tc][0];
  rr[0]=a00; rr[1]=a01; rr[2]=a02; rr[3]=a03;
  rr[4]=a10; rr[5]=a11; rr[6]=a12; rr[7]=a13;
  rr[8]=a20; rr[9]=a21; rr[10]=a22; rr[11]=a23;
  rr[12]=a30; rr[13]=a31; rr[14]=a32; rr[15]=a33;
  __syncthreads();
  const int tc2 = t >> 2, j = t & 3;
#pragma unroll
  for (int i = 0; i < 4; ++i) {
    const int x = i * 4 + j;
    Am[(i0 + i) * 256 + t] =
        red[0][tc2][x] + red[1][tc2][x] + red[2][tc2][x] + red[3][tc2][x];
  }
}

// ---------------- NS phase B: Y=XA rows, Z=YA rows, combine ----------------
// quint: X' = QA*X + QB*Y + QC*Z ; else X' = 1.5*X - 0.5*Y
__global__ __launch_bounds__(256) void k_pB(const float* __restrict__ X,
                                            const float* __restrict__ A,
                                            float* __restrict__ Xn,
                                            const int quint) {
  const int m = blockIdx.x >> 6, g = blockIdx.x & 63, i0 = g * 4;
  const int t = threadIdx.x, tq = t >> 6, tc = t & 63;
  const float* Xm = X + (size_t)m * MSZ;
  const float* Am = A + (size_t)m * MSZ;
  float* Xo = Xn + (size_t)m * MSZ;
  __shared__ float xr[4][260];        // xr[q][kk*4+i] = X[i0+i][q*64+kk]
  __shared__ float yr[4][260];        // same layout for Y rows
  __shared__ float red[4][64][17];

  {  // stage X rows i0..i0+3 (transposed layout)
    const int ri = t >> 6, f4 = t & 63;
    const float4 xv = *(const float4*)(Xm + (i0 + ri) * 256 + f4 * 4);
#pragma unroll
    for (int e = 0; e < 4; ++e) {
      const int k = f4 * 4 + e;
      xr[k >> 6][(k & 63) * 4 + ri] = (&xv.x)[e];
    }
  }
  __syncthreads();

  const float4* A4 = (const float4*)Am;
  const int kbase = tq * 64;
  const int tc2 = t >> 2, jj = t & 3;

  // ---- stage 1: Y rows = X[i0..i0+3,:] * A ----
  {
    float a00=0,a01=0,a02=0,a03=0, a10=0,a11=0,a12=0,a13=0;
    float a20=0,a21=0,a22=0,a23=0, a30=0,a31=0,a32=0,a33=0;
#pragma unroll 8
    for (int kk = 0; kk < 64; ++kk) {
      const float4 av = A4[(kbase + kk) * 64 + tc];
      const float4 pv = *(const float4*)&xr[tq][kk * 4];
      a00 += pv.x*av.x; a01 += pv.x*av.y; a02 += pv.x*av.z; a03 += pv.x*av.w;
      a10 += pv.y*av.x; a11 += pv.y*av.y; a12 += pv.y*av.z; a13 += pv.y*av.w;
      a20 += pv.z*av.x; a21 += pv.z*av.y; a22 += pv.z*av.z; a23 += pv.z*av.w;
      a30 += pv.w*av.x; a31 += pv.w*av.y; a32 += pv.w*av.z; a33 += pv.w*av.w;
    }
    float* rr = &red[tq][tc][0];
    rr[0]=a00; rr[1]=a01; rr[2]=a02; rr[3]=a03;
    rr[4]=a10; rr[5]=a11; rr[6]=a12; rr[7]=a13;
    rr[8]=a20; rr[9]=a21; rr[10]=a22; rr[11]=a23;
    rr[12]=a30; rr[13]=a31; rr[14]=a32; rr[15]=a33;
  }
  __syncthreads();

  float yv[4];
#pragma unroll
  for (int i = 0; i < 4; ++i) {
    const int x = i * 4 + jj;
    yv[i] = red[0][tc2][x] + red[1][tc2][x] + red[2][tc2][x] + red[3][tc2][x];
  }

  if (!quint) {  // cubic: X' = 1.5*X - 0.5*Y
#pragma unroll
    for (int i = 0; i < 4; ++i)
      Xo[(i0 + i) * 256 + t] = 1.5f * Xm[(i0 + i) * 256 + t] - 0.5f * yv[i];
    return;
  }

  // stash Y rows in transposed layout for stage 2 (c = t)
#pragma unroll
  for (int i = 0; i < 4; ++i)
    yr[t >> 6][(t & 63) * 4 + i] = yv[i];
  __syncthreads();

  // ---- stage 2: Z rows = Y[i0..i0+3,:] * A ----
  {
    float a00=0,a01=0,a02=0,a03=0, a10=0,a11=0,a12=0,a13=0;
    float a20=0,a21=0,a22=0,a23=0, a30=0,a31=0,a32=0,a33=0;
#pragma unroll 8
    for (int kk = 0; kk < 64; ++kk) {
      const float4 av = A4[(kbase + kk) * 64 + tc];
      const float4 pv = *(const float4*)&yr[tq][kk * 4];
      a00 += pv.x*av.x; a01 += pv.x*av.y; a02 += pv.x*av.z; a03 += pv.x*av.w;
      a10 += pv.y*av.x; a11 += pv.y*av.y; a12 += pv.y*av.z; a13 += pv.y*av.w;
      a20 += pv.z*av.x; a21 += pv.z*av.y; a22 += pv.z*av.z; a23 += pv.z*av.w;
      a30 += pv.w*av.x; a31 += pv.w*av.y; a32 += pv.w*av.z; a33 += pv.w*av.w;
    }
    __syncthreads();  // all stage-1 reads of red done before overwrite
    float* rr = &red[tq][tc][0];
    rr[0]=a00; rr[1]=a01; rr[2]=a02; rr[3]=a03;
    rr[4]=a10; rr[5]=a11; rr[6]=a12; rr[7]=a13;
    rr[8]=a20; rr[9]=a21; rr[10]=a22; rr[11]=a23;
    rr[12]=a30; rr[13]=a31; rr[14]=a32; rr[15]=a33;
  }
  __syncthreads();

#pragma unroll
  for (int i = 0; i < 4; ++i) {
    const int x = i * 4 + jj;
    const float zv = red[0][tc2][x] + red[1][tc2][x] + red[2][tc2][x] + red[3][tc2][x];
    Xo[(i0 + i) * 256 + t] =
        QA * Xm[(i0 + i) * 256 + t] + QB * yv[i] + QC * zv;
  }
}

// ---------------- K4: output assembly ----------------
__global__ __launch_bounds__(256) void k_out(const float* __restrict__ sp,
                                             const float* __restrict__ P,
                                             const int* __restrict__ sel,
                                             float* __restrict__ out) {
  const int t = threadIdx.x;
  if (blockIdx.x < 128) {
    const int b = blockIdx.x;
    __shared__ float hd[256];
    hd[t] = sp[(size_t)b * Kd + t];
    __syncthreads();
    const int s = sel[b];
    if (s < 0) {
      out[(size_t)b * Kd + t] = hd[t];
    } else {
      const float4* prow = (const float4*)(P + (size_t)s * MSZ + t * 256);
      float acc = 0.f;
#pragma unroll 8
      for (int j4 = 0; j4 < 64; ++j4) {
        const float4 p = prow[j4];
        acc += p.x * hd[4 * j4 + 0] + p.y * hd[4 * j4 + 1] +
               p.z * hd[4 * j4 + 2] + p.w * hd[4 * j4 + 3];
      }
      out[(size_t)b * Kd + t] = hd[t] + 0.1f * acc;
    }
  } else {
    const int ci = blockIdx.x - 128;
    const float4* in4 = (const float4*)sp;
    float4* out4 = (float4*)out;
    const int total = Bn * (Kd / 4);
    for (int i = ci * 256 + t; i < total; i += 2048 * 256) {
      const int pos = i & ((Kd / 4) - 1);
      if (pos >= Qd / 4) out4[i] = in4[i];
    }
  }
}

// ---------------- host ----------------
extern "C" void kernel_launch(void* const* d_in, const int* in_sizes, int n_in,
                              void* d_out, int out_size, void* d_ws, size_t ws_size,
                              hipStream_t stream) {
  (void)in_sizes; (void)n_in; (void)out_size; (void)ws_size;
  const float* sp = (const float*)d_in[0];
  const float* W1 = (const float*)d_in[1];
  const float* b1 = (const float*)d_in[2];
  const float* W2 = (const float*)d_in[3];
  const float* b2 = (const float*)d_in[4];
  const float* W3 = (const float*)d_in[5];
  const float* b3 = (const float*)d_in[6];
  const float* ops = (const float*)d_in[7];
  float* out = (float*)d_out;
  float* ws = (float*)d_ws;

  float* h1p  = ws + OFF_H1P;
  float* h1   = ws + OFF_H1;
  int*   sel  = (int*)(ws + OFF_SEL);
  float* part = ws + OFF_PART;
  float* Xa   = ws + OFF_XA;
  float* Xb   = ws + OFF_XB;
  float* Am   = ws + OFF_AM;

  k_gemm1<<<NCH, 256, 0, stream>>>(sp, W1, h1p);
  k_red<<<256, 256, 0, stream>>>(h1p, b1, h1);
  k_mlp<<<8, 256, 0, stream>>>(h1, W2, b2, W3, b3, sel);
  k_sumsq<<<192, 256, 0, stream>>>(ops, part);
  k_scale<<<192, 256, 0, stream>>>(ops, part, Xa);

  float* X = Xa;
  float* Xn = Xb;
  for (int it = 0; it < 12; ++it) {
    k_pA<<<192, 256, 0, stream>>>(X, Am);
    k_pB<<<192, 256, 0, stream>>>(X, Am, Xn, (it < 8) ? 1 : 0);
    float* tmp = X; X = Xn; Xn = tmp;
  }

  k_out<<<128 + 2048, 256, 0, stream>>>(sp, X, sel, out);
}